// Round 5
// baseline (17328.799 us; speedup 1.0000x reference)
//
#include <hip/hip_runtime.h>

#define NN 100000
#define EE 400000
#define GG 4000
#define EMB 300
#define EMB2 600
#define LL 5
#define BN_EPS 1e-5f
#define BUF_BYTES 120000000ull

__device__ __constant__ int c_atom_off[9] = {0,119,123,135,147,157,163,169,171};

// integer read that works for both int32 and int64 device arrays
static __device__ __forceinline__ int geti(const void* p, int f64, long long i) {
    return f64 ? (int)((const long long*)p)[i] : ((const int*)p)[i];
}

// ---- detect int64 vs int32: int64 arrays have all-zero high words ----
__global__ void k_detect(const int* __restrict__ ei, int* __restrict__ flag) {
    __shared__ int cnt;
    if (threadIdx.x == 0) cnt = 0;
    __syncthreads();
    int z = 0;
    for (int i = threadIdx.x; i < 1024; i += 256)
        if (ei[2 * i + 1] == 0) z++;
    atomicAdd(&cnt, z);
    __syncthreads();
    if (threadIdx.x == 0) *flag = (cnt > 512) ? 1 : 0;
}

// ---------------- node encoder: h[n,c] = sum_f atom_emb[x[n,f]+off[f], c] ----------------
__global__ void k_encode(const void* __restrict__ x, const float* __restrict__ aemb,
                         float* __restrict__ h, const int* __restrict__ flag) {
    __shared__ int xi[4][9];
    const int ty = threadIdx.y, tx = threadIdx.x;
    const int n = blockIdx.x * 4 + ty;
    const int f64 = *flag;
    if (tx < 9) xi[ty][tx] = geti(x, f64, (long long)n * 9 + tx) + c_atom_off[tx];
    __syncthreads();
    if (tx < 75) {
        const int c = tx * 4;
        float s0 = 0.f, s1 = 0.f, s2 = 0.f, s3 = 0.f;
#pragma unroll
        for (int f = 0; f < 9; ++f) {
            const float4 v = *(const float4*)(aemb + (size_t)xi[ty][f] * EMB + c);
            s0 += v.x; s1 += v.y; s2 += v.z; s3 += v.w;
        }
        float4 o; o.x = s0; o.y = s1; o.z = s2; o.w = s3;
        *(float4*)(h + (size_t)n * EMB + c) = o;
    }
}

// ------ message + aggregate: z[dst] += relu(h[src] + bond_ea)  (z pre-initialized to h) ------
__global__ void k_msg(const void* __restrict__ ei, const void* __restrict__ eattr,
                      const float* __restrict__ bemb,
                      const float* __restrict__ h, float* __restrict__ z,
                      const int* __restrict__ flag) {
    __shared__ int es[4][5];
    const int ty = threadIdx.y, tx = threadIdx.x;
    const int e = blockIdx.x * 4 + ty;
    const int f64 = *flag;
    if (tx == 0) {
        es[ty][0] = geti(ei, f64, e);
        es[ty][1] = geti(ei, f64, (long long)EE + e);
        es[ty][2] = geti(eattr, f64, (long long)e * 3 + 0);
        es[ty][3] = geti(eattr, f64, (long long)e * 3 + 1) + 5;
        es[ty][4] = geti(eattr, f64, (long long)e * 3 + 2) + 11;
    }
    __syncthreads();
    if (tx < 75) {
        const int c = tx * 4;
        const int src = es[ty][0], dst = es[ty][1];
        const float4 hv = *(const float4*)(h + (size_t)src * EMB + c);
        float e0 = hv.x, e1 = hv.y, e2 = hv.z, e3 = hv.w;
#pragma unroll
        for (int f = 2; f < 5; ++f) {
            const float4 v = *(const float4*)(bemb + (size_t)es[ty][f] * EMB + c);
            e0 += v.x; e1 += v.y; e2 += v.z; e3 += v.w;
        }
        float* a = z + (size_t)dst * EMB + c;
        atomicAdd(a + 0, fmaxf(e0, 0.f));
        atomicAdd(a + 1, fmaxf(e1, 0.f));
        atomicAdd(a + 2, fmaxf(e2, 0.f));
        atomicAdd(a + 3, fmaxf(e3, 0.f));
    }
}

// ------------- GEMM1a: out[N,300] = A[N,300] @ W[:,0:300] (row stride 600), tiled 64x64 -------------
__global__ __launch_bounds__(256) void k_gemm1a(
    const float* __restrict__ A, const float* __restrict__ W, float* __restrict__ out)
{
    __shared__ float As[16][65];
    __shared__ float Bs[16][65];
    const int tid = threadIdx.x;
    const int tx = tid & 15, ty = tid >> 4;
    const int m0 = blockIdx.y * 64;
    const int n0 = blockIdx.x * 64;
    const int ar = tid >> 2, akg = tid & 3;
    const int brow = tid >> 4, bc4 = (tid & 15) * 4;
    float acc[4][4] = {};

    for (int k0 = 0; k0 < EMB; k0 += 16) {
        {
            const int row = m0 + ar;
            const int k = k0 + akg * 4;
            float4 v; v.x = v.y = v.z = v.w = 0.f;
            if (row < NN && k < EMB)
                v = *(const float4*)(A + (size_t)row * EMB + k);
            As[akg * 4 + 0][ar] = v.x; As[akg * 4 + 1][ar] = v.y;
            As[akg * 4 + 2][ar] = v.z; As[akg * 4 + 3][ar] = v.w;
        }
        {
            const int k = k0 + brow;
            float b0 = 0.f, b1 = 0.f, b2 = 0.f, b3 = 0.f;
            const int col = n0 + bc4;
            if (k < EMB && col < EMB) {  // cols 0..299 of a 600-wide W
                const float4 wv = *(const float4*)(W + (size_t)k * EMB2 + col);
                b0 = wv.x; b1 = wv.y; b2 = wv.z; b3 = wv.w;
            }
            Bs[brow][bc4 + 0] = b0; Bs[brow][bc4 + 1] = b1;
            Bs[brow][bc4 + 2] = b2; Bs[brow][bc4 + 3] = b3;
        }
        __syncthreads();
#pragma unroll
        for (int kk = 0; kk < 16; ++kk) {
            float a0 = As[kk][ty], a1 = As[kk][ty + 16], a2 = As[kk][ty + 32], a3 = As[kk][ty + 48];
            float b0 = Bs[kk][tx], b1 = Bs[kk][tx + 16], b2 = Bs[kk][tx + 32], b3 = Bs[kk][tx + 48];
            acc[0][0] = fmaf(a0, b0, acc[0][0]); acc[0][1] = fmaf(a0, b1, acc[0][1]);
            acc[0][2] = fmaf(a0, b2, acc[0][2]); acc[0][3] = fmaf(a0, b3, acc[0][3]);
            acc[1][0] = fmaf(a1, b0, acc[1][0]); acc[1][1] = fmaf(a1, b1, acc[1][1]);
            acc[1][2] = fmaf(a1, b2, acc[1][2]); acc[1][3] = fmaf(a1, b3, acc[1][3]);
            acc[2][0] = fmaf(a2, b0, acc[2][0]); acc[2][1] = fmaf(a2, b1, acc[2][1]);
            acc[2][2] = fmaf(a2, b2, acc[2][2]); acc[2][3] = fmaf(a2, b3, acc[2][3]);
            acc[3][0] = fmaf(a3, b0, acc[3][0]); acc[3][1] = fmaf(a3, b1, acc[3][1]);
            acc[3][2] = fmaf(a3, b2, acc[3][2]); acc[3][3] = fmaf(a3, b3, acc[3][3]);
        }
        __syncthreads();
    }
#pragma unroll
    for (int i = 0; i < 4; ++i) {
        const int row = m0 + ty + 16 * i;
        if (row < NN) {
#pragma unroll
            for (int j = 0; j < 4; ++j) {
                const int col = n0 + tx + 16 * j;
                if (col < EMB) out[(size_t)row * EMB + col] = acc[i][j];
            }
        }
    }
}

// ------------- GEMM1b in-place: Z[16-row tile] := Z_tile @ W[:,300:600] -------------
// rows staged to LDS before overwrite; rows are block-exclusive -> safe in-place
__global__ __launch_bounds__(320) void k_gemm1b(float* __restrict__ Z, const float* __restrict__ W) {
    __shared__ float a[16 * EMB];                  // 19.2 KB
    const int tx = threadIdx.x, ty = threadIdx.y;  // (80,4)
    const int tid = ty * 80 + tx;
    const size_t base = (size_t)blockIdx.x * 16 * EMB;
    for (int i = tid; i < 16 * EMB / 4; i += 320)
        *(float4*)(a + 4 * i) = *(const float4*)(Z + base + 4 * i);
    __syncthreads();
    if (tx < 75) {
        const int c0 = tx * 4;
        float4 acc[4];
#pragma unroll
        for (int i = 0; i < 4; ++i) acc[i].x = acc[i].y = acc[i].z = acc[i].w = 0.f;
        for (int k = 0; k < EMB; ++k) {
            const float4 w = *(const float4*)(W + (size_t)k * EMB2 + c0);  // cols 300..599 panel
            const float a0 = a[(ty + 0) * EMB + k];
            const float a1 = a[(ty + 4) * EMB + k];
            const float a2 = a[(ty + 8) * EMB + k];
            const float a3 = a[(ty + 12) * EMB + k];
            acc[0].x = fmaf(a0, w.x, acc[0].x); acc[0].y = fmaf(a0, w.y, acc[0].y);
            acc[0].z = fmaf(a0, w.z, acc[0].z); acc[0].w = fmaf(a0, w.w, acc[0].w);
            acc[1].x = fmaf(a1, w.x, acc[1].x); acc[1].y = fmaf(a1, w.y, acc[1].y);
            acc[1].z = fmaf(a1, w.z, acc[1].z); acc[1].w = fmaf(a1, w.w, acc[1].w);
            acc[2].x = fmaf(a2, w.x, acc[2].x); acc[2].y = fmaf(a2, w.y, acc[2].y);
            acc[2].z = fmaf(a2, w.z, acc[2].z); acc[2].w = fmaf(a2, w.w, acc[2].w);
            acc[3].x = fmaf(a3, w.x, acc[3].x); acc[3].y = fmaf(a3, w.y, acc[3].y);
            acc[3].z = fmaf(a3, w.z, acc[3].z); acc[3].w = fmaf(a3, w.w, acc[3].w);
        }
#pragma unroll
        for (int i = 0; i < 4; ++i)
            *(float4*)(Z + base + (size_t)(ty + 4 * i) * EMB + c0) = acc[i];
    }
}

// ------------- fused GEMM2 in-place: P[16-row tile] := relu(BN1([P|Q])) @ W2 -------------
__global__ __launch_bounds__(320) void k_gemm2(
    float* __restrict__ P, const float* __restrict__ Q,
    const float* __restrict__ sc, const float* __restrict__ sh,
    const float* __restrict__ W2)
{
    __shared__ float a[16 * EMB2];                 // 38.4 KB
    const int tx = threadIdx.x, ty = threadIdx.y;  // (80,4)
    const int tid = ty * 80 + tx;
    const size_t base = (size_t)blockIdx.x * 16 * EMB;
    // stage BN1+relu(z1a) from P into cols 0..299
    for (int i4 = tid; i4 < 1200; i4 += 320) {
        const int r = i4 / 75, c = (i4 - r * 75) * 4;
        const float4 v = *(const float4*)(P + base + 4 * i4);
        float* d = a + r * EMB2 + c;
        d[0] = fmaxf(fmaf(v.x, sc[c + 0], sh[c + 0]), 0.f);
        d[1] = fmaxf(fmaf(v.y, sc[c + 1], sh[c + 1]), 0.f);
        d[2] = fmaxf(fmaf(v.z, sc[c + 2], sh[c + 2]), 0.f);
        d[3] = fmaxf(fmaf(v.w, sc[c + 3], sh[c + 3]), 0.f);
    }
    // stage BN1+relu(z1b) from Q into cols 300..599
    for (int i4 = tid; i4 < 1200; i4 += 320) {
        const int r = i4 / 75, c = (i4 - r * 75) * 4 + EMB;
        const float4 v = *(const float4*)(Q + base + 4 * i4);
        float* d = a + r * EMB2 + c;
        d[0] = fmaxf(fmaf(v.x, sc[c + 0], sh[c + 0]), 0.f);
        d[1] = fmaxf(fmaf(v.y, sc[c + 1], sh[c + 1]), 0.f);
        d[2] = fmaxf(fmaf(v.z, sc[c + 2], sh[c + 2]), 0.f);
        d[3] = fmaxf(fmaf(v.w, sc[c + 3], sh[c + 3]), 0.f);
    }
    __syncthreads();
    if (tx < 75) {
        const int c0 = tx * 4;
        float4 acc[4];
#pragma unroll
        for (int i = 0; i < 4; ++i) acc[i].x = acc[i].y = acc[i].z = acc[i].w = 0.f;
        for (int k = 0; k < EMB2; ++k) {
            const float4 w = *(const float4*)(W2 + (size_t)k * EMB + c0);
            const float a0 = a[(ty + 0) * EMB2 + k];
            const float a1 = a[(ty + 4) * EMB2 + k];
            const float a2 = a[(ty + 8) * EMB2 + k];
            const float a3 = a[(ty + 12) * EMB2 + k];
            acc[0].x = fmaf(a0, w.x, acc[0].x); acc[0].y = fmaf(a0, w.y, acc[0].y);
            acc[0].z = fmaf(a0, w.z, acc[0].z); acc[0].w = fmaf(a0, w.w, acc[0].w);
            acc[1].x = fmaf(a1, w.x, acc[1].x); acc[1].y = fmaf(a1, w.y, acc[1].y);
            acc[1].z = fmaf(a1, w.z, acc[1].z); acc[1].w = fmaf(a1, w.w, acc[1].w);
            acc[2].x = fmaf(a2, w.x, acc[2].x); acc[2].y = fmaf(a2, w.y, acc[2].y);
            acc[2].z = fmaf(a2, w.z, acc[2].z); acc[2].w = fmaf(a2, w.w, acc[2].w);
            acc[3].x = fmaf(a3, w.x, acc[3].x); acc[3].y = fmaf(a3, w.y, acc[3].y);
            acc[3].z = fmaf(a3, w.z, acc[3].z); acc[3].w = fmaf(a3, w.w, acc[3].w);
        }
#pragma unroll
        for (int i = 0; i < 4; ++i)
            *(float4*)(P + base + (size_t)(ty + 4 * i) * EMB + c0) = acc[i];
    }
}

// ---------------- per-channel sum / sumsq over N rows (C=300 panels) ----------------
__global__ void k_stats(const float* __restrict__ m, float* __restrict__ sum, float* __restrict__ ss) {
    const int c = blockIdx.x * 256 + threadIdx.x;
    if (c >= EMB) return;
    const int r0 = blockIdx.y * 500;
    const int r1 = r0 + 500;
    float s = 0.f, q = 0.f;
    for (int r = r0; r < r1; ++r) {
        const float v = m[(size_t)r * EMB + c];
        s += v; q += v * v;
    }
    atomicAdd(&sum[c], s);
    atomicAdd(&ss[c], q);
}

__global__ void k_scale(const float* __restrict__ sum, const float* __restrict__ ss,
                        const float* __restrict__ g, const float* __restrict__ b,
                        float* __restrict__ scale, float* __restrict__ shift, int C) {
    const int c = blockIdx.x * 256 + threadIdx.x;
    if (c >= C) return;
    const float invN = 1.0f / (float)NN;
    const float mean = sum[c] * invN;
    const float var = ss[c] * invN - mean * mean;
    const float s = g[c] * rsqrtf(var + BN_EPS);
    scale[c] = s;
    shift[c] = b[c] - mean * s;
}

// ---------------- BN2 apply (+ optional relu), in place on h [N,300] ----------------
__global__ void k_bnapply(float* __restrict__ h, const float* __restrict__ scale,
                          const float* __restrict__ shift, int do_relu) {
    const int g = blockIdx.x * 256 + threadIdx.x;
    if (g >= NN * 75) return;
    const int row = g / 75;
    const int c = (g - row * 75) * 4;
    float4 v = *(float4*)(h + (size_t)row * EMB + c);
    v.x = fmaf(v.x, scale[c + 0], shift[c + 0]);
    v.y = fmaf(v.y, scale[c + 1], shift[c + 1]);
    v.z = fmaf(v.z, scale[c + 2], shift[c + 2]);
    v.w = fmaf(v.w, scale[c + 3], shift[c + 3]);
    if (do_relu) {
        v.x = fmaxf(v.x, 0.f); v.y = fmaxf(v.y, 0.f);
        v.z = fmaxf(v.z, 0.f); v.w = fmaxf(v.w, 0.f);
    }
    *(float4*)(h + (size_t)row * EMB + c) = v;
}

// ---------------- graph pooling into f32 d_out ----------------
__global__ void k_pool(const void* __restrict__ batch, const float* __restrict__ h,
                       float* __restrict__ outg, const int* __restrict__ flag) {
    const int ty = threadIdx.y, tx = threadIdx.x;
    const int n = blockIdx.x * 4 + ty;
    if (tx < 75) {
        const int gph = geti(batch, *flag, n);
        const int c = tx * 4;
        const float4 v = *(const float4*)(h + (size_t)n * EMB + c);
        float* o = outg + (size_t)gph * EMB + c;
        atomicAdd(o + 0, v.x); atomicAdd(o + 1, v.y);
        atomicAdd(o + 2, v.z); atomicAdd(o + 3, v.w);
    }
}

extern "C" void kernel_launch(void* const* d_in, const int* in_sizes, int n_in,
                              void* d_out, int out_size, void* d_ws, size_t ws_size,
                              hipStream_t stream) {
    const void* x     = d_in[0];
    const void* ei    = d_in[1];
    const void* eattr = d_in[2];
    const void* batch = d_in[3];
    const float* aemb = (const float*)d_in[4];
    const float* bemb = (const float*)d_in[5];
    const float* W1   = (const float*)d_in[6];
    const float* g1   = (const float*)d_in[8];
    const float* bt1  = (const float*)d_in[9];
    const float* W2   = (const float*)d_in[10];
    const float* g2   = (const float*)d_in[12];
    const float* bt2  = (const float*)d_in[13];

    // ws: P | Q | stats | flag   = 240 MB + 14.4 KB + 4 B
    char* ws = (char*)d_ws;
    float* P  = (float*)(ws);
    float* Q  = (float*)(ws + BUF_BYTES);
    float* st = (float*)(ws + 2 * BUF_BYTES);
    float* sum1 = st;        float* ss1 = st + 600;
    float* sc1  = st + 1200; float* sh1 = st + 1800;
    float* sum2 = st + 2400; float* ss2 = st + 2700;
    float* sc2  = st + 3000; float* sh2 = st + 3300;
    int* flag = (int*)(ws + 2 * BUF_BYTES + 14400);

    const dim3 blk80x4(80, 4);

    k_detect<<<1, 256, 0, stream>>>((const int*)ei, flag);
    k_encode<<<NN / 4, blk80x4, 0, stream>>>(x, aemb, P, flag);

    for (int i = 0; i < LL; ++i) {
        const float* W1i = W1 + (size_t)i * EMB * EMB2;
        const float* W2i = W2 + (size_t)i * EMB2 * EMB;

        // z (in Q) = h + scatter(relu(h[src]+ea))
        (void)hipMemcpyAsync(Q, P, BUF_BYTES, hipMemcpyDeviceToDevice, stream);
        (void)hipMemsetAsync(st, 0, 3600 * sizeof(float), stream);
        k_msg<<<EE / 4, blk80x4, 0, stream>>>(ei, eattr, bemb, P, Q, flag);

        // z1a = z @ W1[:,0:300] -> P (h dead); z1b = z @ W1[:,300:600] in-place over Q
        k_gemm1a<<<dim3(5, 1563), 256, 0, stream>>>(Q, W1i, P);
        k_gemm1b<<<NN / 16, blk80x4, 0, stream>>>(Q, W1i + EMB);

        k_stats<<<dim3(2, 200), 256, 0, stream>>>(P, sum1, ss1);
        k_stats<<<dim3(2, 200), 256, 0, stream>>>(Q, sum1 + EMB, ss1 + EMB);
        k_scale<<<3, 256, 0, stream>>>(sum1, ss1, g1 + (size_t)i * EMB2, bt1 + (size_t)i * EMB2,
                                       sc1, sh1, EMB2);

        // h_new = relu(BN1([P|Q])) @ W2, in-place over P
        k_gemm2<<<NN / 16, blk80x4, 0, stream>>>(P, Q, sc1, sh1, W2i);

        k_stats<<<dim3(2, 200), 256, 0, stream>>>(P, sum2, ss2);
        k_scale<<<2, 256, 0, stream>>>(sum2, ss2, g2 + (size_t)i * EMB, bt2 + (size_t)i * EMB,
                                       sc2, sh2, EMB);
        k_bnapply<<<(NN * 75 + 255) / 256, 256, 0, stream>>>(P, sc2, sh2, (i < LL - 1) ? 1 : 0);
    }

    (void)hipMemsetAsync(d_out, 0, (size_t)GG * EMB * sizeof(float), stream);
    k_pool<<<NN / 4, blk80x4, 0, stream>>>(batch, P, (float*)d_out, flag);
}

// Round 6
// 8626.080 us; speedup vs baseline: 2.0089x; 2.0089x over previous
//
#include <hip/hip_runtime.h>

#define NN 100000
#define EE 400000
#define GG 4000
#define EMB 300
#define EMB2 600
#define LL 5
#define BN_EPS 1e-5f
#define BUF_BYTES 120000000ull

__device__ __constant__ int c_atom_off[9] = {0,119,123,135,147,157,163,169,171};

// integer read that works for both int32 and int64 device arrays
static __device__ __forceinline__ int geti(const void* p, int f64, long long i) {
    return f64 ? (int)((const long long*)p)[i] : ((const int*)p)[i];
}

// ---- detect int64 vs int32: int64 arrays have all-zero high words ----
__global__ void k_detect(const int* __restrict__ ei, int* __restrict__ flag) {
    __shared__ int cnt;
    if (threadIdx.x == 0) cnt = 0;
    __syncthreads();
    int z = 0;
    for (int i = threadIdx.x; i < 1024; i += 256)
        if (ei[2 * i + 1] == 0) z++;
    atomicAdd(&cnt, z);
    __syncthreads();
    if (threadIdx.x == 0) *flag = (cnt > 512) ? 1 : 0;
}

// ---------------- node encoder: h[n,c] = sum_f atom_emb[x[n,f]+off[f], c] ----------------
__global__ void k_encode(const void* __restrict__ x, const float* __restrict__ aemb,
                         float* __restrict__ h, const int* __restrict__ flag) {
    __shared__ int xi[4][9];
    const int ty = threadIdx.y, tx = threadIdx.x;
    const int n = blockIdx.x * 4 + ty;
    const int f64 = *flag;
    if (tx < 9) xi[ty][tx] = geti(x, f64, (long long)n * 9 + tx) + c_atom_off[tx];
    __syncthreads();
    if (tx < 75) {
        const int c = tx * 4;
        float s0 = 0.f, s1 = 0.f, s2 = 0.f, s3 = 0.f;
#pragma unroll
        for (int f = 0; f < 9; ++f) {
            const float4 v = *(const float4*)(aemb + (size_t)xi[ty][f] * EMB + c);
            s0 += v.x; s1 += v.y; s2 += v.z; s3 += v.w;
        }
        float4 o; o.x = s0; o.y = s1; o.z = s2; o.w = s3;
        *(float4*)(h + (size_t)n * EMB + c) = o;
    }
}

// ---------------- CSR build ----------------
__global__ void k_deg(const void* __restrict__ ei, int* __restrict__ deg,
                      const int* __restrict__ flag) {
    const int e = blockIdx.x * 256 + threadIdx.x;
    if (e < EE) atomicAdd(&deg[geti(ei, *flag, (long long)EE + e)], 1);
}

// single-block exclusive scan of deg[NN] -> rowstart[NN+1] and cursor[NN]
__global__ __launch_bounds__(1024) void k_scan(const int* __restrict__ deg,
                                               int* __restrict__ rowstart,
                                               int* __restrict__ cursor) {
    __shared__ int part[1024];
    const int t = threadIdx.x;
    const int c0 = t * 98;
    const int c1 = (c0 + 98 < NN) ? c0 + 98 : NN;
    int s = 0;
    for (int i = c0; i < c1; ++i) s += deg[i];
    part[t] = s;
    __syncthreads();
    for (int off = 1; off < 1024; off <<= 1) {
        int v = (t >= off) ? part[t - off] : 0;
        __syncthreads();
        part[t] += v;
        __syncthreads();
    }
    int run = part[t] - s;   // exclusive base of this chunk
    for (int i = c0; i < c1; ++i) {
        rowstart[i] = run; cursor[i] = run;
        run += deg[i];
    }
    if (c1 == NN && c0 <= NN) rowstart[NN] = run;
}

// elist[pos] = src*64 + combo  (combo = b0*12 + b1*2 + b2, < 60)
__global__ void k_scatter(const void* __restrict__ ei, const void* __restrict__ eattr,
                          int* __restrict__ cursor, int* __restrict__ elist,
                          const int* __restrict__ flag) {
    const int e = blockIdx.x * 256 + threadIdx.x;
    if (e >= EE) return;
    const int f64 = *flag;
    const int src = geti(ei, f64, e);
    const int dst = geti(ei, f64, (long long)EE + e);
    const int b0 = geti(eattr, f64, (long long)e * 3 + 0);
    const int b1 = geti(eattr, f64, (long long)e * 3 + 1);
    const int b2 = geti(eattr, f64, (long long)e * 3 + 2);
    const int pos = atomicAdd(&cursor[dst], 1);
    elist[pos] = src * 64 + b0 * 12 + b1 * 2 + b2;
}

// combined bond table: ebc[cb] = bemb[b0] + bemb[5+b1] + bemb[11+b2]
__global__ void k_ebc(const float* __restrict__ bemb, float* __restrict__ ebc) {
    const int cb = blockIdx.x;
    const int tx = threadIdx.x;
    if (tx >= 75) return;
    const int b0 = cb / 12, b1 = (cb / 2) % 6, b2 = cb & 1;
    const int c = tx * 4;
    const float4 v0 = *(const float4*)(bemb + (size_t)b0 * EMB + c);
    const float4 v1 = *(const float4*)(bemb + (size_t)(5 + b1) * EMB + c);
    const float4 v2 = *(const float4*)(bemb + (size_t)(11 + b2) * EMB + c);
    float4 o; o.x = v0.x + v1.x + v2.x; o.y = v0.y + v1.y + v2.y;
    o.z = v0.z + v1.z + v2.z; o.w = v0.w + v1.w + v2.w;
    *(float4*)(ebc + (size_t)cb * EMB + c) = o;
}

// ------ gather-aggregate: z[n] = h[n] + sum_{e in in(n)} relu(h[src_e] + ebc[combo_e]) ------
__global__ void k_gather(const int* __restrict__ rowstart, const int* __restrict__ elist,
                         const float* __restrict__ ebc,
                         const float* __restrict__ h, float* __restrict__ z) {
    const int ty = threadIdx.y, tx = threadIdx.x;
    const int n = blockIdx.x * 4 + ty;
    if (tx >= 75) return;
    const int c = tx * 4;
    const int s = rowstart[n], e = rowstart[n + 1];
    float4 acc = *(const float4*)(h + (size_t)n * EMB + c);
    for (int j = s; j < e; ++j) {
        const int packed = elist[j];
        const int src = packed >> 6, cb = packed & 63;
        const float4 hv = *(const float4*)(h + (size_t)src * EMB + c);
        const float4 ev = *(const float4*)(ebc + (size_t)cb * EMB + c);
        acc.x += fmaxf(hv.x + ev.x, 0.f);
        acc.y += fmaxf(hv.y + ev.y, 0.f);
        acc.z += fmaxf(hv.z + ev.z, 0.f);
        acc.w += fmaxf(hv.w + ev.w, 0.f);
    }
    *(float4*)(z + (size_t)n * EMB + c) = acc;
}

// ------------- GEMM1a: out[N,300] = A[N,300] @ W[:,0:300] (row stride 600), tiled 64x64 -------------
__global__ __launch_bounds__(256) void k_gemm1a(
    const float* __restrict__ A, const float* __restrict__ W, float* __restrict__ out)
{
    __shared__ float As[16][65];
    __shared__ float Bs[16][65];
    const int tid = threadIdx.x;
    const int tx = tid & 15, ty = tid >> 4;
    const int m0 = blockIdx.y * 64;
    const int n0 = blockIdx.x * 64;
    const int ar = tid >> 2, akg = tid & 3;
    const int brow = tid >> 4, bc4 = (tid & 15) * 4;
    float acc[4][4] = {};

    for (int k0 = 0; k0 < EMB; k0 += 16) {
        {
            const int row = m0 + ar;
            const int k = k0 + akg * 4;
            float4 v; v.x = v.y = v.z = v.w = 0.f;
            if (row < NN && k < EMB)
                v = *(const float4*)(A + (size_t)row * EMB + k);
            As[akg * 4 + 0][ar] = v.x; As[akg * 4 + 1][ar] = v.y;
            As[akg * 4 + 2][ar] = v.z; As[akg * 4 + 3][ar] = v.w;
        }
        {
            const int k = k0 + brow;
            float b0 = 0.f, b1 = 0.f, b2 = 0.f, b3 = 0.f;
            const int col = n0 + bc4;
            if (k < EMB && col < EMB) {
                const float4 wv = *(const float4*)(W + (size_t)k * EMB2 + col);
                b0 = wv.x; b1 = wv.y; b2 = wv.z; b3 = wv.w;
            }
            Bs[brow][bc4 + 0] = b0; Bs[brow][bc4 + 1] = b1;
            Bs[brow][bc4 + 2] = b2; Bs[brow][bc4 + 3] = b3;
        }
        __syncthreads();
#pragma unroll
        for (int kk = 0; kk < 16; ++kk) {
            float a0 = As[kk][ty], a1 = As[kk][ty + 16], a2 = As[kk][ty + 32], a3 = As[kk][ty + 48];
            float b0 = Bs[kk][tx], b1 = Bs[kk][tx + 16], b2 = Bs[kk][tx + 32], b3 = Bs[kk][tx + 48];
            acc[0][0] = fmaf(a0, b0, acc[0][0]); acc[0][1] = fmaf(a0, b1, acc[0][1]);
            acc[0][2] = fmaf(a0, b2, acc[0][2]); acc[0][3] = fmaf(a0, b3, acc[0][3]);
            acc[1][0] = fmaf(a1, b0, acc[1][0]); acc[1][1] = fmaf(a1, b1, acc[1][1]);
            acc[1][2] = fmaf(a1, b2, acc[1][2]); acc[1][3] = fmaf(a1, b3, acc[1][3]);
            acc[2][0] = fmaf(a2, b0, acc[2][0]); acc[2][1] = fmaf(a2, b1, acc[2][1]);
            acc[2][2] = fmaf(a2, b2, acc[2][2]); acc[2][3] = fmaf(a2, b3, acc[2][3]);
            acc[3][0] = fmaf(a3, b0, acc[3][0]); acc[3][1] = fmaf(a3, b1, acc[3][1]);
            acc[3][2] = fmaf(a3, b2, acc[3][2]); acc[3][3] = fmaf(a3, b3, acc[3][3]);
        }
        __syncthreads();
    }
#pragma unroll
    for (int i = 0; i < 4; ++i) {
        const int row = m0 + ty + 16 * i;
        if (row < NN) {
#pragma unroll
            for (int j = 0; j < 4; ++j) {
                const int col = n0 + tx + 16 * j;
                if (col < EMB) out[(size_t)row * EMB + col] = acc[i][j];
            }
        }
    }
}

// ------------- GEMM1b in-place: Z[16-row tile] := Z_tile @ W[:,300:600] -------------
__global__ __launch_bounds__(320) void k_gemm1b(float* __restrict__ Z, const float* __restrict__ W) {
    __shared__ float a[16 * EMB];
    const int tx = threadIdx.x, ty = threadIdx.y;
    const int tid = ty * 80 + tx;
    const size_t base = (size_t)blockIdx.x * 16 * EMB;
    for (int i = tid; i < 16 * EMB / 4; i += 320)
        *(float4*)(a + 4 * i) = *(const float4*)(Z + base + 4 * i);
    __syncthreads();
    if (tx < 75) {
        const int c0 = tx * 4;
        float4 acc[4];
#pragma unroll
        for (int i = 0; i < 4; ++i) acc[i].x = acc[i].y = acc[i].z = acc[i].w = 0.f;
        for (int k = 0; k < EMB; ++k) {
            const float4 w = *(const float4*)(W + (size_t)k * EMB2 + c0);
            const float a0 = a[(ty + 0) * EMB + k];
            const float a1 = a[(ty + 4) * EMB + k];
            const float a2 = a[(ty + 8) * EMB + k];
            const float a3 = a[(ty + 12) * EMB + k];
            acc[0].x = fmaf(a0, w.x, acc[0].x); acc[0].y = fmaf(a0, w.y, acc[0].y);
            acc[0].z = fmaf(a0, w.z, acc[0].z); acc[0].w = fmaf(a0, w.w, acc[0].w);
            acc[1].x = fmaf(a1, w.x, acc[1].x); acc[1].y = fmaf(a1, w.y, acc[1].y);
            acc[1].z = fmaf(a1, w.z, acc[1].z); acc[1].w = fmaf(a1, w.w, acc[1].w);
            acc[2].x = fmaf(a2, w.x, acc[2].x); acc[2].y = fmaf(a2, w.y, acc[2].y);
            acc[2].z = fmaf(a2, w.z, acc[2].z); acc[2].w = fmaf(a2, w.w, acc[2].w);
            acc[3].x = fmaf(a3, w.x, acc[3].x); acc[3].y = fmaf(a3, w.y, acc[3].y);
            acc[3].z = fmaf(a3, w.z, acc[3].z); acc[3].w = fmaf(a3, w.w, acc[3].w);
        }
#pragma unroll
        for (int i = 0; i < 4; ++i)
            *(float4*)(Z + base + (size_t)(ty + 4 * i) * EMB + c0) = acc[i];
    }
}

// ------------- fused GEMM2 in-place: P[16-row tile] := relu(BN1([P|Q])) @ W2 -------------
__global__ __launch_bounds__(320) void k_gemm2(
    float* __restrict__ P, const float* __restrict__ Q,
    const float* __restrict__ sc, const float* __restrict__ sh,
    const float* __restrict__ W2)
{
    __shared__ float a[16 * EMB2];
    const int tx = threadIdx.x, ty = threadIdx.y;
    const int tid = ty * 80 + tx;
    const size_t base = (size_t)blockIdx.x * 16 * EMB;
    for (int i4 = tid; i4 < 1200; i4 += 320) {
        const int r = i4 / 75, c = (i4 - r * 75) * 4;
        const float4 v = *(const float4*)(P + base + 4 * i4);
        float* d = a + r * EMB2 + c;
        d[0] = fmaxf(fmaf(v.x, sc[c + 0], sh[c + 0]), 0.f);
        d[1] = fmaxf(fmaf(v.y, sc[c + 1], sh[c + 1]), 0.f);
        d[2] = fmaxf(fmaf(v.z, sc[c + 2], sh[c + 2]), 0.f);
        d[3] = fmaxf(fmaf(v.w, sc[c + 3], sh[c + 3]), 0.f);
    }
    for (int i4 = tid; i4 < 1200; i4 += 320) {
        const int r = i4 / 75, c = (i4 - r * 75) * 4 + EMB;
        const float4 v = *(const float4*)(Q + base + 4 * i4);
        float* d = a + r * EMB2 + c;
        d[0] = fmaxf(fmaf(v.x, sc[c + 0], sh[c + 0]), 0.f);
        d[1] = fmaxf(fmaf(v.y, sc[c + 1], sh[c + 1]), 0.f);
        d[2] = fmaxf(fmaf(v.z, sc[c + 2], sh[c + 2]), 0.f);
        d[3] = fmaxf(fmaf(v.w, sc[c + 3], sh[c + 3]), 0.f);
    }
    __syncthreads();
    if (tx < 75) {
        const int c0 = tx * 4;
        float4 acc[4];
#pragma unroll
        for (int i = 0; i < 4; ++i) acc[i].x = acc[i].y = acc[i].z = acc[i].w = 0.f;
        for (int k = 0; k < EMB2; ++k) {
            const float4 w = *(const float4*)(W2 + (size_t)k * EMB + c0);
            const float a0 = a[(ty + 0) * EMB2 + k];
            const float a1 = a[(ty + 4) * EMB2 + k];
            const float a2 = a[(ty + 8) * EMB2 + k];
            const float a3 = a[(ty + 12) * EMB2 + k];
            acc[0].x = fmaf(a0, w.x, acc[0].x); acc[0].y = fmaf(a0, w.y, acc[0].y);
            acc[0].z = fmaf(a0, w.z, acc[0].z); acc[0].w = fmaf(a0, w.w, acc[0].w);
            acc[1].x = fmaf(a1, w.x, acc[1].x); acc[1].y = fmaf(a1, w.y, acc[1].y);
            acc[1].z = fmaf(a1, w.z, acc[1].z); acc[1].w = fmaf(a1, w.w, acc[1].w);
            acc[2].x = fmaf(a2, w.x, acc[2].x); acc[2].y = fmaf(a2, w.y, acc[2].y);
            acc[2].z = fmaf(a2, w.z, acc[2].z); acc[2].w = fmaf(a2, w.w, acc[2].w);
            acc[3].x = fmaf(a3, w.x, acc[3].x); acc[3].y = fmaf(a3, w.y, acc[3].y);
            acc[3].z = fmaf(a3, w.z, acc[3].z); acc[3].w = fmaf(a3, w.w, acc[3].w);
        }
#pragma unroll
        for (int i = 0; i < 4; ++i)
            *(float4*)(P + base + (size_t)(ty + 4 * i) * EMB + c0) = acc[i];
    }
}

// ---------------- per-channel sum / sumsq over N rows (C=300 panels) ----------------
__global__ void k_stats(const float* __restrict__ m, float* __restrict__ sum, float* __restrict__ ss) {
    const int c = blockIdx.x * 256 + threadIdx.x;
    if (c >= EMB) return;
    const int r0 = blockIdx.y * 500;
    const int r1 = r0 + 500;
    float s = 0.f, q = 0.f;
    for (int r = r0; r < r1; ++r) {
        const float v = m[(size_t)r * EMB + c];
        s += v; q += v * v;
    }
    atomicAdd(&sum[c], s);
    atomicAdd(&ss[c], q);
}

__global__ void k_scale(const float* __restrict__ sum, const float* __restrict__ ss,
                        const float* __restrict__ g, const float* __restrict__ b,
                        float* __restrict__ scale, float* __restrict__ shift, int C) {
    const int c = blockIdx.x * 256 + threadIdx.x;
    if (c >= C) return;
    const float invN = 1.0f / (float)NN;
    const float mean = sum[c] * invN;
    const float var = ss[c] * invN - mean * mean;
    const float s = g[c] * rsqrtf(var + BN_EPS);
    scale[c] = s;
    shift[c] = b[c] - mean * s;
}

// ---------------- BN2 apply (+ optional relu), in place on h [N,300] ----------------
__global__ void k_bnapply(float* __restrict__ h, const float* __restrict__ scale,
                          const float* __restrict__ shift, int do_relu) {
    const int g = blockIdx.x * 256 + threadIdx.x;
    if (g >= NN * 75) return;
    const int row = g / 75;
    const int c = (g - row * 75) * 4;
    float4 v = *(float4*)(h + (size_t)row * EMB + c);
    v.x = fmaf(v.x, scale[c + 0], shift[c + 0]);
    v.y = fmaf(v.y, scale[c + 1], shift[c + 1]);
    v.z = fmaf(v.z, scale[c + 2], shift[c + 2]);
    v.w = fmaf(v.w, scale[c + 3], shift[c + 3]);
    if (do_relu) {
        v.x = fmaxf(v.x, 0.f); v.y = fmaxf(v.y, 0.f);
        v.z = fmaxf(v.z, 0.f); v.w = fmaxf(v.w, 0.f);
    }
    *(float4*)(h + (size_t)row * EMB + c) = v;
}

// ---------------- pooling: batch is sorted -> per-graph binary search + block reduce ----------------
__global__ void k_poolg(const void* __restrict__ batch, const float* __restrict__ h,
                        float* __restrict__ out, const int* __restrict__ flag) {
    __shared__ float red[4][EMB];
    const int g = blockIdx.x;
    const int f64 = *flag;
    int lo = 0, hi = NN;
    while (lo < hi) { int mid = (lo + hi) >> 1; if (geti(batch, f64, mid) < g) lo = mid + 1; else hi = mid; }
    const int s = lo;
    hi = NN;
    while (lo < hi) { int mid = (lo + hi) >> 1; if (geti(batch, f64, mid) < g + 1) lo = mid + 1; else hi = mid; }
    const int e = lo;
    const int tx = threadIdx.x, ty = threadIdx.y;
    if (tx < 75) {
        const int c = tx * 4;
        float4 acc; acc.x = acc.y = acc.z = acc.w = 0.f;
        for (int r = s + ty; r < e; r += 4) {
            const float4 v = *(const float4*)(h + (size_t)r * EMB + c);
            acc.x += v.x; acc.y += v.y; acc.z += v.z; acc.w += v.w;
        }
        *(float4*)(&red[ty][c]) = acc;
    }
    __syncthreads();
    if (ty == 0 && tx < 75) {
        const int c = tx * 4;
        float4 o;
        o.x = red[0][c + 0] + red[1][c + 0] + red[2][c + 0] + red[3][c + 0];
        o.y = red[0][c + 1] + red[1][c + 1] + red[2][c + 1] + red[3][c + 1];
        o.z = red[0][c + 2] + red[1][c + 2] + red[2][c + 2] + red[3][c + 2];
        o.w = red[0][c + 3] + red[1][c + 3] + red[2][c + 3] + red[3][c + 3];
        *(float4*)(out + (size_t)g * EMB + c) = o;
    }
}

extern "C" void kernel_launch(void* const* d_in, const int* in_sizes, int n_in,
                              void* d_out, int out_size, void* d_ws, size_t ws_size,
                              hipStream_t stream) {
    const void* x     = d_in[0];
    const void* ei    = d_in[1];
    const void* eattr = d_in[2];
    const void* batch = d_in[3];
    const float* aemb = (const float*)d_in[4];
    const float* bemb = (const float*)d_in[5];
    const float* W1   = (const float*)d_in[6];
    const float* g1   = (const float*)d_in[8];
    const float* bt1  = (const float*)d_in[9];
    const float* W2   = (const float*)d_in[10];
    const float* g2   = (const float*)d_in[12];
    const float* bt2  = (const float*)d_in[13];

    // ws: P | Q | stats(16KB) | csr (~3MB)   total ~243 MB
    char* ws = (char*)d_ws;
    float* P  = (float*)(ws);
    float* Q  = (float*)(ws + BUF_BYTES);
    char*  aux = ws + 2 * BUF_BYTES;
    float* st = (float*)(aux);                    // 3600 floats
    int* flag     = (int*)(aux + 16384);
    int* deg      = (int*)(aux + 16384 + 64);             // NN ints
    int* rowstart = (int*)(aux + 16384 + 64 + 400064);    // NN+1 ints
    int* cursor   = (int*)(aux + 16384 + 64 + 800128);    // NN ints
    int* elist    = (int*)(aux + 16384 + 64 + 1200192);   // EE ints
    float* ebc    = (float*)(aux + 16384 + 64 + 2800192); // 60*300 floats
    float* sum1 = st;        float* ss1 = st + 600;
    float* sc1  = st + 1200; float* sh1 = st + 1800;
    float* sum2 = st + 2400; float* ss2 = st + 2700;
    float* sc2  = st + 3000; float* sh2 = st + 3300;

    const dim3 blk80x4(80, 4);

    k_detect<<<1, 256, 0, stream>>>((const int*)ei, flag);

    // CSR build (once per launch, reused for all layers)
    (void)hipMemsetAsync(deg, 0, NN * sizeof(int), stream);
    k_deg<<<(EE + 255) / 256, 256, 0, stream>>>(ei, deg, flag);
    k_scan<<<1, 1024, 0, stream>>>(deg, rowstart, cursor);
    k_scatter<<<(EE + 255) / 256, 256, 0, stream>>>(ei, eattr, cursor, elist, flag);
    k_ebc<<<60, 80, 0, stream>>>(bemb, ebc);

    k_encode<<<NN / 4, blk80x4, 0, stream>>>(x, aemb, P, flag);

    for (int i = 0; i < LL; ++i) {
        const float* W1i = W1 + (size_t)i * EMB * EMB2;
        const float* W2i = W2 + (size_t)i * EMB2 * EMB;

        (void)hipMemsetAsync(st, 0, 3600 * sizeof(float), stream);

        // z (in Q) = h + sum relu(h[src]+ea)   — gather, no atomics
        k_gather<<<NN / 4, blk80x4, 0, stream>>>(rowstart, elist, ebc, P, Q);

        // z1a = z @ W1[:,0:300] -> P (h dead); z1b = z @ W1[:,300:600] in-place over Q
        k_gemm1a<<<dim3(5, 1563), 256, 0, stream>>>(Q, W1i, P);
        k_gemm1b<<<NN / 16, blk80x4, 0, stream>>>(Q, W1i + EMB);

        k_stats<<<dim3(2, 200), 256, 0, stream>>>(P, sum1, ss1);
        k_stats<<<dim3(2, 200), 256, 0, stream>>>(Q, sum1 + EMB, ss1 + EMB);
        k_scale<<<3, 256, 0, stream>>>(sum1, ss1, g1 + (size_t)i * EMB2, bt1 + (size_t)i * EMB2,
                                       sc1, sh1, EMB2);

        // h_new = relu(BN1([P|Q])) @ W2, in-place over P
        k_gemm2<<<NN / 16, blk80x4, 0, stream>>>(P, Q, sc1, sh1, W2i);

        k_stats<<<dim3(2, 200), 256, 0, stream>>>(P, sum2, ss2);
        k_scale<<<2, 256, 0, stream>>>(sum2, ss2, g2 + (size_t)i * EMB, bt2 + (size_t)i * EMB,
                                       sc2, sh2, EMB);
        k_bnapply<<<(NN * 75 + 255) / 256, 256, 0, stream>>>(P, sc2, sh2, (i < LL - 1) ? 1 : 0);
    }

    k_poolg<<<GG, blk80x4, 0, stream>>>(batch, P, (float*)d_out, flag);
}

// Round 7
// 6766.544 us; speedup vs baseline: 2.5610x; 1.2748x over previous
//
#include <hip/hip_runtime.h>

#define NN 100000
#define EE 400000
#define GG 4000
#define EMB 300
#define EMB2 600
#define LL 5
#define BN_EPS 1e-5f
#define BUF_BYTES 120000000ull

typedef __attribute__((ext_vector_type(8))) short bf16x8;
typedef __attribute__((ext_vector_type(4))) float f32x4;

__device__ __constant__ int c_atom_off[9] = {0,119,123,135,147,157,163,169,171};

static __device__ __forceinline__ float u16tof(unsigned short u) {
    return __uint_as_float(((unsigned int)u) << 16);
}
// f32 -> bf16 bits, round-to-nearest-even
static __device__ __forceinline__ unsigned short ftobf(float f) {
    unsigned int u = __float_as_uint(f);
    unsigned int r = 0x7fffu + ((u >> 16) & 1u);
    return (unsigned short)((u + r) >> 16);
}
static __device__ __forceinline__ int geti(const void* p, int f64, long long i) {
    return f64 ? (int)((const long long*)p)[i] : ((const int*)p)[i];
}
// split one float into bf16 hi + bf16 lo (lo = rnd(x - hi))
static __device__ __forceinline__ void split8(const float* vv, bf16x8& hi, bf16x8& lo) {
#pragma unroll
    for (int e = 0; e < 8; ++e) {
        const unsigned short h = ftobf(vv[e]);
        hi[e] = (short)h;
        lo[e] = (short)ftobf(vv[e] - u16tof(h));
    }
}
static __device__ __forceinline__ f32x4 mfma16(bf16x8 a, bf16x8 b, f32x4 c) {
    return __builtin_amdgcn_mfma_f32_16x16x32_bf16(a, b, c, 0, 0, 0);
}

__global__ void k_detect(const int* __restrict__ ei, int* __restrict__ flag) {
    __shared__ int cnt;
    if (threadIdx.x == 0) cnt = 0;
    __syncthreads();
    int z = 0;
    for (int i = threadIdx.x; i < 1024; i += 256)
        if (ei[2 * i + 1] == 0) z++;
    atomicAdd(&cnt, z);
    __syncthreads();
    if (threadIdx.x == 0) *flag = (cnt > 512) ? 1 : 0;
}

__global__ void k_encode(const void* __restrict__ x, const float* __restrict__ aemb,
                         float* __restrict__ h, const int* __restrict__ flag) {
    __shared__ int xi[4][9];
    const int ty = threadIdx.y, tx = threadIdx.x;
    const int n = blockIdx.x * 4 + ty;
    const int f64 = *flag;
    if (tx < 9) xi[ty][tx] = geti(x, f64, (long long)n * 9 + tx) + c_atom_off[tx];
    __syncthreads();
    if (tx < 75) {
        const int c = tx * 4;
        float s0 = 0.f, s1 = 0.f, s2 = 0.f, s3 = 0.f;
#pragma unroll
        for (int f = 0; f < 9; ++f) {
            const float4 v = *(const float4*)(aemb + (size_t)xi[ty][f] * EMB + c);
            s0 += v.x; s1 += v.y; s2 += v.z; s3 += v.w;
        }
        float4 o; o.x = s0; o.y = s1; o.z = s2; o.w = s3;
        *(float4*)(h + (size_t)n * EMB + c) = o;
    }
}

// ---------------- CSR build ----------------
__global__ void k_deg(const void* __restrict__ ei, int* __restrict__ deg,
                      const int* __restrict__ flag) {
    const int e = blockIdx.x * 256 + threadIdx.x;
    if (e < EE) atomicAdd(&deg[geti(ei, *flag, (long long)EE + e)], 1);
}

__global__ __launch_bounds__(1024) void k_scan(const int* __restrict__ deg,
                                               int* __restrict__ rowstart,
                                               int* __restrict__ cursor) {
    __shared__ int part[1024];
    const int t = threadIdx.x;
    const int c0 = t * 98;
    const int c1 = (c0 + 98 < NN) ? c0 + 98 : NN;
    int s = 0;
    for (int i = c0; i < c1; ++i) s += deg[i];
    part[t] = s;
    __syncthreads();
    for (int off = 1; off < 1024; off <<= 1) {
        int v = (t >= off) ? part[t - off] : 0;
        __syncthreads();
        part[t] += v;
        __syncthreads();
    }
    int run = part[t] - s;
    for (int i = c0; i < c1; ++i) {
        rowstart[i] = run; cursor[i] = run;
        run += deg[i];
    }
    if (c1 == NN && c0 <= NN) rowstart[NN] = run;
}

__global__ void k_scatter(const void* __restrict__ ei, const void* __restrict__ eattr,
                          int* __restrict__ cursor, int* __restrict__ elist,
                          const int* __restrict__ flag) {
    const int e = blockIdx.x * 256 + threadIdx.x;
    if (e >= EE) return;
    const int f64 = *flag;
    const int src = geti(ei, f64, e);
    const int dst = geti(ei, f64, (long long)EE + e);
    const int b0 = geti(eattr, f64, (long long)e * 3 + 0);
    const int b1 = geti(eattr, f64, (long long)e * 3 + 1);
    const int b2 = geti(eattr, f64, (long long)e * 3 + 2);
    const int pos = atomicAdd(&cursor[dst], 1);
    elist[pos] = src * 64 + b0 * 12 + b1 * 2 + b2;
}

__global__ void k_ebc(const float* __restrict__ bemb, float* __restrict__ ebc) {
    const int cb = blockIdx.x;
    const int tx = threadIdx.x;
    if (tx >= 75) return;
    const int b0 = cb / 12, b1 = (cb / 2) % 6, b2 = cb & 1;
    const int c = tx * 4;
    const float4 v0 = *(const float4*)(bemb + (size_t)b0 * EMB + c);
    const float4 v1 = *(const float4*)(bemb + (size_t)(5 + b1) * EMB + c);
    const float4 v2 = *(const float4*)(bemb + (size_t)(11 + b2) * EMB + c);
    float4 o; o.x = v0.x + v1.x + v2.x; o.y = v0.y + v1.y + v2.y;
    o.z = v0.z + v1.z + v2.z; o.w = v0.w + v1.w + v2.w;
    *(float4*)(ebc + (size_t)cb * EMB + c) = o;
}

__global__ void k_gather(const int* __restrict__ rowstart, const int* __restrict__ elist,
                         const float* __restrict__ ebc,
                         const float* __restrict__ h, float* __restrict__ z) {
    const int ty = threadIdx.y, tx = threadIdx.x;
    const int n = blockIdx.x * 4 + ty;
    if (tx >= 75) return;
    const int c = tx * 4;
    const int s = rowstart[n], e = rowstart[n + 1];
    float4 acc = *(const float4*)(h + (size_t)n * EMB + c);
    for (int j = s; j < e; ++j) {
        const int packed = elist[j];
        const int src = packed >> 6, cb = packed & 63;
        const float4 hv = *(const float4*)(h + (size_t)src * EMB + c);
        const float4 ev = *(const float4*)(ebc + (size_t)cb * EMB + c);
        acc.x += fmaxf(hv.x + ev.x, 0.f);
        acc.y += fmaxf(hv.y + ev.y, 0.f);
        acc.z += fmaxf(hv.z + ev.z, 0.f);
        acc.w += fmaxf(hv.w + ev.w, 0.f);
    }
    *(float4*)(z + (size_t)n * EMB + c) = acc;
}

// ---- weight split/transpose: W1 [300][600] f32 -> [608 cols][320 k] bf16 hi/lo ----
__global__ void k_wconv1(const float* __restrict__ W, unsigned short* __restrict__ hi,
                         unsigned short* __restrict__ lo) {
    const int idx = blockIdx.x * 256 + threadIdx.x;
    if (idx >= 608 * 320) return;
    const int n = idx / 320, k = idx - n * 320;
    const float w = (n < EMB2 && k < EMB) ? W[(size_t)k * EMB2 + n] : 0.f;
    const unsigned short h = ftobf(w);
    hi[idx] = h;
    lo[idx] = ftobf(w - u16tof(h));
}
// ---- W2 [600][300] f32 -> [320 cols][608 k] bf16 hi/lo ----
__global__ void k_wconv2(const float* __restrict__ W, unsigned short* __restrict__ hi,
                         unsigned short* __restrict__ lo) {
    const int idx = blockIdx.x * 256 + threadIdx.x;
    if (idx >= 320 * 608) return;
    const int n = idx / 608, k = idx - n * 608;
    const float w = (n < EMB && k < EMB2) ? W[(size_t)k * EMB + n] : 0.f;
    const unsigned short h = ftobf(w);
    hi[idx] = h;
    lo[idx] = ftobf(w - u16tof(h));
}

// ---- MFMA GEMM1: [z1a|z1b] = z(Q) @ W1 ; z1a -> P (cols 0-299), z1b -> Q (cols 300-599) ----
// block = 16 rows, 4 waves split 38 n-tiles stride-4. split-bf16, 3 MFMA per tile.
__global__ __launch_bounds__(256) void k_mfma1(
    const float* __restrict__ Q, const unsigned short* __restrict__ whi,
    const unsigned short* __restrict__ wlo, float* __restrict__ P, float* __restrict__ Qo)
{
    const int lane = threadIdx.x & 63;
    const int wn = threadIdx.x >> 6;
    const int g = lane >> 4, r = lane & 15;
    const int row = blockIdx.x * 16 + r;
    f32x4 acc[10];
#pragma unroll
    for (int i = 0; i < 10; ++i) acc[i] = (f32x4){0.f, 0.f, 0.f, 0.f};

    for (int kt = 0; kt < 10; ++kt) {
        const int kb = kt * 32 + g * 8;
        float vv[8];
        {
            float4 v0 = {0.f,0.f,0.f,0.f}, v1 = {0.f,0.f,0.f,0.f};
            if (kb + 3 < EMB) v0 = *(const float4*)(Q + (size_t)row * EMB + kb);
            if (kb + 7 < EMB) v1 = *(const float4*)(Q + (size_t)row * EMB + kb + 4);
            vv[0]=v0.x; vv[1]=v0.y; vv[2]=v0.z; vv[3]=v0.w;
            vv[4]=v1.x; vv[5]=v1.y; vv[6]=v1.z; vv[7]=v1.w;
        }
        bf16x8 ahi, alo;
        split8(vv, ahi, alo);
#pragma unroll
        for (int t = 0; t < 10; ++t) {
            const int nt = wn + t * 4;
            if (nt >= 38) break;
            const size_t wb = (size_t)(nt * 16 + r) * 320 + kt * 32 + g * 8;
            const bf16x8 bhi = *(const bf16x8*)(whi + wb);
            const bf16x8 blo = *(const bf16x8*)(wlo + wb);
            acc[t] = mfma16(alo, bhi, acc[t]);
            acc[t] = mfma16(ahi, blo, acc[t]);
            acc[t] = mfma16(ahi, bhi, acc[t]);
        }
    }
    __syncthreads();   // all A-reads of Q done before Qo writes (same buffer)
    const int orow0 = blockIdx.x * 16 + g * 4;
#pragma unroll
    for (int t = 0; t < 10; ++t) {
        const int nt = wn + t * 4;
        if (nt >= 38) break;
        const int col = nt * 16 + r;
#pragma unroll
        for (int j = 0; j < 4; ++j) {
            const int orow = orow0 + j;
            const float val = acc[t][j];
            if (col < EMB)       P[(size_t)orow * EMB + col] = val;
            else if (col < EMB2) Qo[(size_t)orow * EMB + (col - EMB)] = val;
        }
    }
}

// ---- MFMA GEMM2: h = relu(BN1([P|Q])) @ W2 -> P in-place. 20 n-tiles, 5 per wave ----
__global__ __launch_bounds__(256) void k_mfma2(
    float* __restrict__ P, const float* __restrict__ Qa,
    const float* __restrict__ sc, const float* __restrict__ sh,
    const unsigned short* __restrict__ whi, const unsigned short* __restrict__ wlo)
{
    const int lane = threadIdx.x & 63;
    const int wn = threadIdx.x >> 6;
    const int g = lane >> 4, r = lane & 15;
    const int row = blockIdx.x * 16 + r;
    f32x4 acc[5];
#pragma unroll
    for (int i = 0; i < 5; ++i) acc[i] = (f32x4){0.f, 0.f, 0.f, 0.f};

    for (int kt = 0; kt < 19; ++kt) {
        const int kb = kt * 32 + g * 8;
        float vv[8];
#pragma unroll
        for (int half = 0; half < 2; ++half) {
            const int k4 = kb + 4 * half;
            float4 v = {0.f,0.f,0.f,0.f};
            if (k4 + 3 < EMB2) {
                const float* src = (k4 < EMB) ? (P + (size_t)row * EMB + k4)
                                              : (Qa + (size_t)row * EMB + (k4 - EMB));
                v = *(const float4*)src;
                const float4 s4 = *(const float4*)(sc + k4);
                const float4 h4 = *(const float4*)(sh + k4);
                v.x = fmaxf(fmaf(v.x, s4.x, h4.x), 0.f);
                v.y = fmaxf(fmaf(v.y, s4.y, h4.y), 0.f);
                v.z = fmaxf(fmaf(v.z, s4.z, h4.z), 0.f);
                v.w = fmaxf(fmaf(v.w, s4.w, h4.w), 0.f);
            }
            vv[half * 4 + 0] = v.x; vv[half * 4 + 1] = v.y;
            vv[half * 4 + 2] = v.z; vv[half * 4 + 3] = v.w;
        }
        bf16x8 ahi, alo;
        split8(vv, ahi, alo);
#pragma unroll
        for (int t = 0; t < 5; ++t) {
            const int nt = wn + t * 4;
            const size_t wb = (size_t)(nt * 16 + r) * 608 + kt * 32 + g * 8;
            const bf16x8 bhi = *(const bf16x8*)(whi + wb);
            const bf16x8 blo = *(const bf16x8*)(wlo + wb);
            acc[t] = mfma16(alo, bhi, acc[t]);
            acc[t] = mfma16(ahi, blo, acc[t]);
            acc[t] = mfma16(ahi, bhi, acc[t]);
        }
    }
    __syncthreads();   // all A-reads of P done before in-place P writes
    const int orow0 = blockIdx.x * 16 + g * 4;
#pragma unroll
    for (int t = 0; t < 5; ++t) {
        const int nt = wn + t * 4;
        const int col = nt * 16 + r;
        if (col < EMB) {
#pragma unroll
            for (int j = 0; j < 4; ++j)
                P[(size_t)(orow0 + j) * EMB + col] = acc[t][j];
        }
    }
}

__global__ void k_stats(const float* __restrict__ m, float* __restrict__ sum, float* __restrict__ ss) {
    const int c = blockIdx.x * 256 + threadIdx.x;
    if (c >= EMB) return;
    const int r0 = blockIdx.y * 500;
    const int r1 = r0 + 500;
    float s = 0.f, q = 0.f;
    for (int r = r0; r < r1; ++r) {
        const float v = m[(size_t)r * EMB + c];
        s += v; q += v * v;
    }
    atomicAdd(&sum[c], s);
    atomicAdd(&ss[c], q);
}

__global__ void k_scale(const float* __restrict__ sum, const float* __restrict__ ss,
                        const float* __restrict__ g, const float* __restrict__ b,
                        float* __restrict__ scale, float* __restrict__ shift, int C) {
    const int c = blockIdx.x * 256 + threadIdx.x;
    if (c >= C) return;
    const float invN = 1.0f / (float)NN;
    const float mean = sum[c] * invN;
    const float var = ss[c] * invN - mean * mean;
    const float s = g[c] * rsqrtf(var + BN_EPS);
    scale[c] = s;
    shift[c] = b[c] - mean * s;
}

__global__ void k_bnapply(float* __restrict__ h, const float* __restrict__ scale,
                          const float* __restrict__ shift, int do_relu) {
    const int g = blockIdx.x * 256 + threadIdx.x;
    if (g >= NN * 75) return;
    const int row = g / 75;
    const int c = (g - row * 75) * 4;
    float4 v = *(float4*)(h + (size_t)row * EMB + c);
    v.x = fmaf(v.x, scale[c + 0], shift[c + 0]);
    v.y = fmaf(v.y, scale[c + 1], shift[c + 1]);
    v.z = fmaf(v.z, scale[c + 2], shift[c + 2]);
    v.w = fmaf(v.w, scale[c + 3], shift[c + 3]);
    if (do_relu) {
        v.x = fmaxf(v.x, 0.f); v.y = fmaxf(v.y, 0.f);
        v.z = fmaxf(v.z, 0.f); v.w = fmaxf(v.w, 0.f);
    }
    *(float4*)(h + (size_t)row * EMB + c) = v;
}

__global__ void k_poolg(const void* __restrict__ batch, const float* __restrict__ h,
                        float* __restrict__ out, const int* __restrict__ flag) {
    __shared__ float red[4][EMB];
    const int g = blockIdx.x;
    const int f64 = *flag;
    int lo = 0, hi = NN;
    while (lo < hi) { int mid = (lo + hi) >> 1; if (geti(batch, f64, mid) < g) lo = mid + 1; else hi = mid; }
    const int s = lo;
    hi = NN;
    while (lo < hi) { int mid = (lo + hi) >> 1; if (geti(batch, f64, mid) < g + 1) lo = mid + 1; else hi = mid; }
    const int e = lo;
    const int tx = threadIdx.x, ty = threadIdx.y;
    if (tx < 75) {
        const int c = tx * 4;
        float4 acc; acc.x = acc.y = acc.z = acc.w = 0.f;
        for (int r = s + ty; r < e; r += 4) {
            const float4 v = *(const float4*)(h + (size_t)r * EMB + c);
            acc.x += v.x; acc.y += v.y; acc.z += v.z; acc.w += v.w;
        }
        *(float4*)(&red[ty][c]) = acc;
    }
    __syncthreads();
    if (ty == 0 && tx < 75) {
        const int c = tx * 4;
        float4 o;
        o.x = red[0][c + 0] + red[1][c + 0] + red[2][c + 0] + red[3][c + 0];
        o.y = red[0][c + 1] + red[1][c + 1] + red[2][c + 1] + red[3][c + 1];
        o.z = red[0][c + 2] + red[1][c + 2] + red[2][c + 2] + red[3][c + 2];
        o.w = red[0][c + 3] + red[1][c + 3] + red[2][c + 3] + red[3][c + 3];
        *(float4*)(out + (size_t)g * EMB + c) = o;
    }
}

extern "C" void kernel_launch(void* const* d_in, const int* in_sizes, int n_in,
                              void* d_out, int out_size, void* d_ws, size_t ws_size,
                              hipStream_t stream) {
    const void* x     = d_in[0];
    const void* ei    = d_in[1];
    const void* eattr = d_in[2];
    const void* batch = d_in[3];
    const float* aemb = (const float*)d_in[4];
    const float* bemb = (const float*)d_in[5];
    const float* W1   = (const float*)d_in[6];
    const float* g1   = (const float*)d_in[8];
    const float* bt1  = (const float*)d_in[9];
    const float* W2   = (const float*)d_in[10];
    const float* g2   = (const float*)d_in[12];
    const float* bt2  = (const float*)d_in[13];

    // ws: P | Q | stats | csr | split-weights    total ~245 MB... keep under proven 244.8:
    char* ws = (char*)d_ws;
    float* P  = (float*)(ws);
    float* Q  = (float*)(ws + BUF_BYTES);
    char*  aux = ws + 2 * BUF_BYTES;
    float* st = (float*)(aux);                             // 3600 floats
    int* flag     = (int*)(aux + 16384);
    int* deg      = (int*)(aux + 16384 + 64);              // NN ints
    int* rowstart = (int*)(aux + 16384 + 64 + 400064);     // NN+1 ints
    int* cursor   = (int*)(aux + 16384 + 64 + 800128);     // NN ints
    int* elist    = (int*)(aux + 16384 + 64 + 1200192);    // EE ints
    float* ebc    = (float*)(aux + 16384 + 64 + 2800192);  // 60*300 floats -> +72000
    unsigned short* wt1hi = (unsigned short*)(aux + 2888640);             // 608*320*2 = 389120
    unsigned short* wt1lo = (unsigned short*)(aux + 2888640 + 389120);
    unsigned short* wt2hi = (unsigned short*)(aux + 2888640 + 778240);    // 320*608*2
    unsigned short* wt2lo = (unsigned short*)(aux + 2888640 + 1167360);   // ends ~ +1.56 MB
    float* sum1 = st;        float* ss1 = st + 600;
    float* sc1  = st + 1200; float* sh1 = st + 1800;
    float* sum2 = st + 2400; float* ss2 = st + 2700;
    float* sc2  = st + 3000; float* sh2 = st + 3300;

    const dim3 blk80x4(80, 4);

    k_detect<<<1, 256, 0, stream>>>((const int*)ei, flag);

    (void)hipMemsetAsync(deg, 0, NN * sizeof(int), stream);
    k_deg<<<(EE + 255) / 256, 256, 0, stream>>>(ei, deg, flag);
    k_scan<<<1, 1024, 0, stream>>>(deg, rowstart, cursor);
    k_scatter<<<(EE + 255) / 256, 256, 0, stream>>>(ei, eattr, cursor, elist, flag);
    k_ebc<<<60, 80, 0, stream>>>(bemb, ebc);

    k_encode<<<NN / 4, blk80x4, 0, stream>>>(x, aemb, P, flag);

    for (int i = 0; i < LL; ++i) {
        const float* W1i = W1 + (size_t)i * EMB * EMB2;
        const float* W2i = W2 + (size_t)i * EMB2 * EMB;

        (void)hipMemsetAsync(st, 0, 3600 * sizeof(float), stream);
        k_wconv1<<<(608 * 320 + 255) / 256, 256, 0, stream>>>(W1i, wt1hi, wt1lo);
        k_wconv2<<<(320 * 608 + 255) / 256, 256, 0, stream>>>(W2i, wt2hi, wt2lo);

        // z (in Q) = h + sum relu(h[src]+ea)
        k_gather<<<NN / 4, blk80x4, 0, stream>>>(rowstart, elist, ebc, P, Q);

        // z1 = z @ W1 via MFMA: z1a -> P, z1b -> Q (in-place, barrier-protected)
        k_mfma1<<<NN / 16, 256, 0, stream>>>(Q, wt1hi, wt1lo, P, Q);

        k_stats<<<dim3(2, 200), 256, 0, stream>>>(P, sum1, ss1);
        k_stats<<<dim3(2, 200), 256, 0, stream>>>(Q, sum1 + EMB, ss1 + EMB);
        k_scale<<<3, 256, 0, stream>>>(sum1, ss1, g1 + (size_t)i * EMB2, bt1 + (size_t)i * EMB2,
                                       sc1, sh1, EMB2);

        // h_new = relu(BN1([P|Q])) @ W2 -> P in-place via MFMA
        k_mfma2<<<NN / 16, 256, 0, stream>>>(P, Q, sc1, sh1, wt2hi, wt2lo);

        k_stats<<<dim3(2, 200), 256, 0, stream>>>(P, sum2, ss2);
        k_scale<<<2, 256, 0, stream>>>(sum2, ss2, g2 + (size_t)i * EMB, bt2 + (size_t)i * EMB,
                                       sc2, sh2, EMB);
        k_bnapply<<<(NN * 75 + 255) / 256, 256, 0, stream>>>(P, sc2, sh2, (i < LL - 1) ? 1 : 0);
    }

    k_poolg<<<GG, blk80x4, 0, stream>>>(batch, P, (float*)d_out, flag);
}